// Round 1
// baseline (431.933 us; speedup 1.0000x reference)
//
#include <hip/hip_runtime.h>
#include <hip/hip_bf16.h>
#include <math.h>

#define EPS 1e-6f

// ---------------------------------------------------------------------------
// K1: y[m,p] = sum_c x[b,c,hw] * w1[p,c]     (m = b*4096 + hw)
// 64x64 tile, BK=64 (2 k-chunks). A loaded m-coalesced (x is hw-contiguous),
// B loaded k-coalesced. LDS k-major with +4 pad (aligned b128, 2-way max).
// ---------------------------------------------------------------------------
__global__ __launch_bounds__(256) void k_conv1x1(const float* __restrict__ x,
                                                 const float* __restrict__ w1,
                                                 float* __restrict__ y) {
  __shared__ float As[64][68];  // [k(c)][m]
  __shared__ float Bs[64][68];  // [k(c)][p]
  const int t = threadIdx.x;
  const int m0 = blockIdx.x * 64, p0 = blockIdx.y * 64;
  const int b = m0 >> 12, hw0 = m0 & 4095;
  const int ml = t & 63, c0 = t >> 6;
  const int rl = t >> 2, kq = t & 3;
  const int tn = t & 15, tm = t >> 4;  // tn -> p (output-fastest), tm -> m
  float acc[4][4] = {};
  for (int kk = 0; kk < 128; kk += 64) {
    __syncthreads();
#pragma unroll
    for (int i = 0; i < 16; ++i)
      As[c0 + i * 4][ml] = x[(size_t)(b * 128 + kk + c0 + i * 4) * 4096 + hw0 + ml];
#pragma unroll
    for (int j = 0; j < 4; ++j) {
      const int f = kq + j * 4;
      const float4 v = *(const float4*)(w1 + (size_t)(p0 + rl) * 128 + kk + f * 4);
      Bs[f * 4 + 0][rl] = v.x;
      Bs[f * 4 + 1][rl] = v.y;
      Bs[f * 4 + 2][rl] = v.z;
      Bs[f * 4 + 3][rl] = v.w;
    }
    __syncthreads();
#pragma unroll 8
    for (int k = 0; k < 64; ++k) {
      const float4 a = *(const float4*)(&As[k][tm * 4]);
      const float4 bb = *(const float4*)(&Bs[k][tn * 4]);
      const float av[4] = {a.x, a.y, a.z, a.w};
      const float bv[4] = {bb.x, bb.y, bb.z, bb.w};
#pragma unroll
      for (int i = 0; i < 4; ++i)
#pragma unroll
        for (int j = 0; j < 4; ++j) acc[i][j] += av[i] * bv[j];
    }
  }
#pragma unroll
  for (int i = 0; i < 4; ++i) {
    const float4 v = {acc[i][0], acc[i][1], acc[i][2], acc[i][3]};
    *(float4*)(y + (size_t)(m0 + tm * 4 + i) * 256 + p0 + tn * 4) = v;
  }
}

// ---------------------------------------------------------------------------
// K2: depthwise 3x3 SAME + bias, NHWC layout in/out. One wave = one pixel,
// lane handles a p-quad (float4). Weights staged transposed in LDS.
// ---------------------------------------------------------------------------
__global__ __launch_bounds__(256) void k_dwconv(const float* __restrict__ y,
                                                const float* __restrict__ w3,
                                                const float* __restrict__ b3,
                                                float* __restrict__ xm) {
  __shared__ float wt[9][256];
  __shared__ float bs[256];
  const int t = threadIdx.x;
#pragma unroll
  for (int i = 0; i < 9; ++i) wt[i][t] = w3[t * 9 + i];
  bs[t] = b3[t];
  __syncthreads();
  const int sub = t >> 6;
  const int pq = t & 63;
  const int m = blockIdx.x * 4 + sub;
  const int hw = m & 4095;
  const int h = hw >> 6, w = hw & 63;
  const int bb = m >> 12;
  float4 acc = *(const float4*)(&bs[pq * 4]);
#pragma unroll
  for (int dy = -1; dy <= 1; ++dy) {
    const int hh = h + dy;
    if (hh < 0 || hh > 63) continue;
#pragma unroll
    for (int dx = -1; dx <= 1; ++dx) {
      const int ww = w + dx;
      if (ww < 0 || ww > 63) continue;
      const int idx = (dy + 1) * 3 + (dx + 1);
      const float4 v =
          *(const float4*)(y + (size_t)((bb << 12) + (hh << 6) + ww) * 256 + pq * 4);
      const float4 wv = *(const float4*)(&wt[idx][pq * 4]);
      acc.x += v.x * wv.x;
      acc.y += v.y * wv.y;
      acc.z += v.z * wv.z;
      acc.w += v.w * wv.w;
    }
  }
  *(float4*)(xm + (size_t)m * 256 + pq * 4) = acc;
}

// ---------------------------------------------------------------------------
// K3: xl = relu(xm @ lower_w^T + lb). 64x64 tile, BK=64. Both operands
// k-contiguous row-major -> k-coalesced float4 loads, transposed into LDS.
// ---------------------------------------------------------------------------
__global__ __launch_bounds__(256) void k_lower(const float* __restrict__ xm,
                                               const float* __restrict__ lw,
                                               const float* __restrict__ lb,
                                               float* __restrict__ xl) {
  __shared__ float As[64][68];  // [k][m]
  __shared__ float Bs[64][68];  // [k][n]
  const int t = threadIdx.x;
  const int m0 = blockIdx.x * 64, n0 = blockIdx.y * 64;
  const int rl = t >> 2, kq = t & 3;
  const int tn = t & 15, tm = t >> 4;
  float acc[4][4] = {};
  for (int kk = 0; kk < 256; kk += 64) {
    __syncthreads();
#pragma unroll
    for (int j = 0; j < 4; ++j) {
      const int f = kq + j * 4;
      const float4 a = *(const float4*)(xm + (size_t)(m0 + rl) * 256 + kk + f * 4);
      As[f * 4 + 0][rl] = a.x;
      As[f * 4 + 1][rl] = a.y;
      As[f * 4 + 2][rl] = a.z;
      As[f * 4 + 3][rl] = a.w;
      const float4 bq = *(const float4*)(lw + (size_t)(n0 + rl) * 256 + kk + f * 4);
      Bs[f * 4 + 0][rl] = bq.x;
      Bs[f * 4 + 1][rl] = bq.y;
      Bs[f * 4 + 2][rl] = bq.z;
      Bs[f * 4 + 3][rl] = bq.w;
    }
    __syncthreads();
#pragma unroll 8
    for (int k = 0; k < 64; ++k) {
      const float4 a = *(const float4*)(&As[k][tm * 4]);
      const float4 bb = *(const float4*)(&Bs[k][tn * 4]);
      const float av[4] = {a.x, a.y, a.z, a.w};
      const float bv[4] = {bb.x, bb.y, bb.z, bb.w};
#pragma unroll
      for (int i = 0; i < 4; ++i)
#pragma unroll
        for (int j = 0; j < 4; ++j) acc[i][j] += av[i] * bv[j];
    }
  }
  const float4 bias4 = *(const float4*)(lb + n0 + tn * 4);
  const float bias[4] = {bias4.x, bias4.y, bias4.z, bias4.w};
#pragma unroll
  for (int i = 0; i < 4; ++i) {
    float4 v;
    v.x = fmaxf(acc[i][0] + bias[0], 0.f);
    v.y = fmaxf(acc[i][1] + bias[1], 0.f);
    v.z = fmaxf(acc[i][2] + bias[2], 0.f);
    v.w = fmaxf(acc[i][3] + bias[3], 0.f);
    *(float4*)(xl + (size_t)(m0 + tm * 4 + i) * 256 + n0 + tn * 4) = v;
  }
}

// ---------------------------------------------------------------------------
// K4: per-pixel EM (d=1 collapsed). One wave per pixel; lane owns 4 n-rows.
// c[4][16] in VGPRs; b-update via 64-lane butterfly of 32 partials.
// In-place: reads xl row then overwrites it with feat (no restrict!).
// ---------------------------------------------------------------------------
__global__ __launch_bounds__(256) void k_em(const float* xl,
                                            const float* __restrict__ binit,
                                            const float* __restrict__ xmp,
                                            float* feat) {
  const int lane = threadIdx.x & 63;
  const int m = blockIdx.x * 4 + (threadIdx.x >> 6);
  const float4 s4 = *(const float4*)(xl + (size_t)m * 256 + lane * 4);
  const float s[4] = {s4.x, s4.y, s4.z, s4.w};
  float b[16];
#pragma unroll
  for (int r = 0; r < 16; ++r) {
    const float v = binit[m * 16 + r];
    b[r] = v / fmaxf(fabsf(v), 1e-12f);
  }
  // initial coef: softmax_r(s_n * b_r)
  float c[4][16];
#pragma unroll
  for (int i = 0; i < 4; ++i) {
    float mx = s[i] * b[0];
#pragma unroll
    for (int r = 1; r < 16; ++r) mx = fmaxf(mx, s[i] * b[r]);
    float sum = 0.f;
#pragma unroll
    for (int r = 0; r < 16; ++r) {
      const float e = __expf(s[i] * b[r] - mx);
      c[i][r] = e;
      sum += e;
    }
    const float inv = __fdividef(1.f, sum);
#pragma unroll
    for (int r = 0; r < 16; ++r) c[i][r] *= inv;
  }
  for (int step = 0; step < 6; ++step) {
    // coef: c *= (s*b_r) / (t*b_r + eps), t = sum_r c*b
#pragma unroll
    for (int i = 0; i < 4; ++i) {
      float tt = 0.f;
#pragma unroll
      for (int r = 0; r < 16; ++r) tt += c[i][r] * b[r];
#pragma unroll
      for (int r = 0; r < 16; ++r)
        c[i][r] = c[i][r] * __fdividef(s[i] * b[r], tt * b[r] + EPS);
    }
    // bases: b_k *= (sum_n s_n c_nk) / (sum_n t'_n c_nk + eps)
    float red[32];
#pragma unroll
    for (int r = 0; r < 32; ++r) red[r] = 0.f;
#pragma unroll
    for (int i = 0; i < 4; ++i) {
      float tp = 0.f;
#pragma unroll
      for (int r = 0; r < 16; ++r) tp += c[i][r] * b[r];
#pragma unroll
      for (int r = 0; r < 16; ++r) {
        red[r] += s[i] * c[i][r];
        red[16 + r] += tp * c[i][r];
      }
    }
#pragma unroll
    for (int msk = 1; msk < 64; msk <<= 1) {
#pragma unroll
      for (int r = 0; r < 32; ++r) red[r] += __shfl_xor(red[r], msk, 64);
    }
#pragma unroll
    for (int r = 0; r < 16; ++r)
      b[r] = b[r] * __fdividef(red[r], red[16 + r] + EPS);
  }
  // final coef refresh + xr + feat = relu(xm + xr)
  const float4 xm4 = *(const float4*)(xmp + (size_t)m * 256 + lane * 4);
  const float xmv[4] = {xm4.x, xm4.y, xm4.z, xm4.w};
  float o4[4];
#pragma unroll
  for (int i = 0; i < 4; ++i) {
    float tt = 0.f;
#pragma unroll
    for (int r = 0; r < 16; ++r) tt += c[i][r] * b[r];
    float xr = 0.f;
#pragma unroll
    for (int r = 0; r < 16; ++r) {
      const float cn = c[i][r] * __fdividef(s[i] * b[r], tt * b[r] + EPS);
      xr += b[r] * cn;
    }
    o4[i] = fmaxf(xmv[i] + xr, 0.f);
  }
  const float4 outv = {o4[0], o4[1], o4[2], o4[3]};
  *(float4*)(feat + (size_t)m * 256 + lane * 4) = outv;
}

// ---------------------------------------------------------------------------
// K5: pooling phase 1 — per (b, 64-row chunk) partial sum/max per channel.
// ---------------------------------------------------------------------------
__global__ __launch_bounds__(256) void k_pool1(const float* __restrict__ feat,
                                               float* __restrict__ psum,
                                               float* __restrict__ pmax) {
  const int t = threadIdx.x;
  const int b = blockIdx.x >> 6;
  const int ch = blockIdx.x & 63;
  const float* fp = feat + (size_t)(b * 4096 + ch * 64) * 256 + t;
  float sum = 0.f, mx = -1e30f;
#pragma unroll 8
  for (int r = 0; r < 64; ++r) {
    const float v = fp[(size_t)r * 256];
    sum += v;
    mx = fmaxf(mx, v);
  }
  psum[(size_t)blockIdx.x * 256 + t] = sum;
  pmax[(size_t)blockIdx.x * 256 + t] = mx;
}

// ---------------------------------------------------------------------------
// K6: finish pooling + channel-attention MLP + sigmoid. One block per b.
// ---------------------------------------------------------------------------
__global__ __launch_bounds__(256) void k_att(const float* __restrict__ psum,
                                             const float* __restrict__ pmax,
                                             const float* __restrict__ ca1,
                                             const float* __restrict__ ca2,
                                             float* __restrict__ attv,
                                             float* __restrict__ out_att) {
  __shared__ float sA[256], sM[256], sH[64];
  const int t = threadIdx.x;
  const int b = blockIdx.x;
  float sum = 0.f, mx = -1e30f;
#pragma unroll 8
  for (int ch = 0; ch < 64; ++ch) {
    sum += psum[(size_t)(b * 64 + ch) * 256 + t];
    mx = fmaxf(mx, pmax[(size_t)(b * 64 + ch) * 256 + t]);
  }
  sA[t] = sum * (1.0f / 4096.0f);
  sM[t] = mx;
  __syncthreads();
  if (t < 64) {
    float ha = 0.f, hm = 0.f;
#pragma unroll 8
    for (int p = 0; p < 256; ++p) {
      const float w = ca1[t * 256 + p];
      ha += sA[p] * w;
      hm += sM[p] * w;
    }
    sH[t] = fmaxf(ha, 0.f) + fmaxf(hm, 0.f);
  }
  __syncthreads();
  float logit = 0.f;
#pragma unroll 8
  for (int a = 0; a < 64; ++a) logit += sH[a] * ca2[t * 64 + a];
  const float av = 1.0f / (1.0f + expf(-logit));
  attv[b * 256 + t] = av;
  out_att[b * 256 + t] = av;
}

// ---------------------------------------------------------------------------
// K7: out[b,o,hw] = sum_p feat[m,p]*att[b,p]*fc_w[o,p] + fc_b[o].
// att folded into A-tile load. Output written m-coalesced (float4 over m).
// ---------------------------------------------------------------------------
__global__ __launch_bounds__(256) void k_fc(const float* __restrict__ feat,
                                            const float* __restrict__ attv,
                                            const float* __restrict__ fw,
                                            const float* __restrict__ fb,
                                            float* __restrict__ out) {
  __shared__ float As[64][68];  // [k(p)][m]
  __shared__ float Bs[64][68];  // [k(p)][o]
  const int t = threadIdx.x;
  const int m0 = blockIdx.x * 64, o0 = blockIdx.y * 64;
  const int b = m0 >> 12, hw0 = m0 & 4095;
  const int rl = t >> 2, kq = t & 3;
  const int tm = t & 15, tn = t >> 4;  // tm -> m (output-fastest), tn -> o
  float acc[4][4] = {};                // [i over m][j over o]
  for (int kk = 0; kk < 256; kk += 64) {
    __syncthreads();
#pragma unroll
    for (int j = 0; j < 4; ++j) {
      const int f = kq + j * 4;
      const float4 a = *(const float4*)(feat + (size_t)(m0 + rl) * 256 + kk + f * 4);
      const float4 av = *(const float4*)(attv + b * 256 + kk + f * 4);
      As[f * 4 + 0][rl] = a.x * av.x;
      As[f * 4 + 1][rl] = a.y * av.y;
      As[f * 4 + 2][rl] = a.z * av.z;
      As[f * 4 + 3][rl] = a.w * av.w;
      const float4 bq = *(const float4*)(fw + (size_t)(o0 + rl) * 256 + kk + f * 4);
      Bs[f * 4 + 0][rl] = bq.x;
      Bs[f * 4 + 1][rl] = bq.y;
      Bs[f * 4 + 2][rl] = bq.z;
      Bs[f * 4 + 3][rl] = bq.w;
    }
    __syncthreads();
#pragma unroll 8
    for (int k = 0; k < 64; ++k) {
      const float4 a = *(const float4*)(&As[k][tm * 4]);
      const float4 bb = *(const float4*)(&Bs[k][tn * 4]);
      const float av[4] = {a.x, a.y, a.z, a.w};
      const float bv[4] = {bb.x, bb.y, bb.z, bb.w};
#pragma unroll
      for (int i = 0; i < 4; ++i)
#pragma unroll
        for (int j = 0; j < 4; ++j) acc[i][j] += av[i] * bv[j];
    }
  }
#pragma unroll
  for (int j = 0; j < 4; ++j) {
    const int o = o0 + tn * 4 + j;
    const float bias = fb[o];
    const float4 v = {acc[0][j] + bias, acc[1][j] + bias, acc[2][j] + bias,
                      acc[3][j] + bias};
    *(float4*)(out + (size_t)b * 524288 + (size_t)o * 4096 + hw0 + tm * 4) = v;
  }
}

extern "C" void kernel_launch(void* const* d_in, const int* in_sizes, int n_in,
                              void* d_out, int out_size, void* d_ws, size_t ws_size,
                              hipStream_t stream) {
  const float* x = (const float*)d_in[0];
  const float* w1 = (const float*)d_in[1];
  const float* w3 = (const float*)d_in[2];
  const float* b3 = (const float*)d_in[3];
  const float* lw = (const float*)d_in[4];
  const float* lb = (const float*)d_in[5];
  const float* ca1 = (const float*)d_in[6];
  const float* ca2 = (const float*)d_in[7];
  const float* fw = (const float*)d_in[8];
  const float* fb = (const float*)d_in[9];
  const float* binit = (const float*)d_in[10];

  float* ws = (float*)d_ws;
  float* bufA = ws;            // y -> xl -> feat   (M*256)
  float* bufB = ws + 4194304;  // xm                (M*256)
  float* psum = ws + 8388608;  // 4*64*256
  float* pmax = psum + 65536;
  float* attv = pmax + 65536;  // 1024
  float* out = (float*)d_out;
  float* out_att = out + 2097152;

  const dim3 blk(256);
  k_conv1x1<<<dim3(256, 4), blk, 0, stream>>>(x, w1, bufA);
  k_dwconv<<<dim3(4096), blk, 0, stream>>>(bufA, w3, b3, bufB);
  k_lower<<<dim3(256, 4), blk, 0, stream>>>(bufB, lw, lb, bufA);
  k_em<<<dim3(4096), blk, 0, stream>>>(bufA, binit, bufB, bufA);
  k_pool1<<<dim3(256), blk, 0, stream>>>(bufA, psum, pmax);
  k_att<<<dim3(4), blk, 0, stream>>>(psum, pmax, ca1, ca2, attv, out_att);
  k_fc<<<dim3(256, 2), blk, 0, stream>>>(bufA, attv, fw, fb, out);
}

// Round 2
// 336.384 us; speedup vs baseline: 1.2840x; 1.2840x over previous
//
#include <hip/hip_runtime.h>
#include <hip/hip_bf16.h>
#include <math.h>

#define EPS 1e-6f

// ---------------------------------------------------------------------------
// K1: y[m,p] = sum_c x[b,c,hw] * w1[p,c]     (m = b*4096 + hw)
// ---------------------------------------------------------------------------
__global__ __launch_bounds__(256) void k_conv1x1(const float* __restrict__ x,
                                                 const float* __restrict__ w1,
                                                 float* __restrict__ y) {
  __shared__ float As[64][68];  // [k(c)][m]
  __shared__ float Bs[64][68];  // [k(c)][p]
  const int t = threadIdx.x;
  const int m0 = blockIdx.x * 64, p0 = blockIdx.y * 64;
  const int b = m0 >> 12, hw0 = m0 & 4095;
  const int ml = t & 63, c0 = t >> 6;
  const int rl = t >> 2, kq = t & 3;
  const int tn = t & 15, tm = t >> 4;
  float acc[4][4] = {};
  for (int kk = 0; kk < 128; kk += 64) {
    __syncthreads();
#pragma unroll
    for (int i = 0; i < 16; ++i)
      As[c0 + i * 4][ml] = x[(size_t)(b * 128 + kk + c0 + i * 4) * 4096 + hw0 + ml];
#pragma unroll
    for (int j = 0; j < 4; ++j) {
      const int f = kq + j * 4;
      const float4 v = *(const float4*)(w1 + (size_t)(p0 + rl) * 128 + kk + f * 4);
      Bs[f * 4 + 0][rl] = v.x;
      Bs[f * 4 + 1][rl] = v.y;
      Bs[f * 4 + 2][rl] = v.z;
      Bs[f * 4 + 3][rl] = v.w;
    }
    __syncthreads();
#pragma unroll 8
    for (int k = 0; k < 64; ++k) {
      const float4 a = *(const float4*)(&As[k][tm * 4]);
      const float4 bb = *(const float4*)(&Bs[k][tn * 4]);
      const float av[4] = {a.x, a.y, a.z, a.w};
      const float bv[4] = {bb.x, bb.y, bb.z, bb.w};
#pragma unroll
      for (int i = 0; i < 4; ++i)
#pragma unroll
        for (int j = 0; j < 4; ++j) acc[i][j] += av[i] * bv[j];
    }
  }
#pragma unroll
  for (int i = 0; i < 4; ++i) {
    const float4 v = {acc[i][0], acc[i][1], acc[i][2], acc[i][3]};
    *(float4*)(y + (size_t)(m0 + tm * 4 + i) * 256 + p0 + tn * 4) = v;
  }
}

// ---------------------------------------------------------------------------
// K2: depthwise 3x3 SAME + bias, NHWC layout in/out.
// ---------------------------------------------------------------------------
__global__ __launch_bounds__(256) void k_dwconv(const float* __restrict__ y,
                                                const float* __restrict__ w3,
                                                const float* __restrict__ b3,
                                                float* __restrict__ xm) {
  __shared__ float wt[9][256];
  __shared__ float bs[256];
  const int t = threadIdx.x;
#pragma unroll
  for (int i = 0; i < 9; ++i) wt[i][t] = w3[t * 9 + i];
  bs[t] = b3[t];
  __syncthreads();
  const int sub = t >> 6;
  const int pq = t & 63;
  const int m = blockIdx.x * 4 + sub;
  const int hw = m & 4095;
  const int h = hw >> 6, w = hw & 63;
  const int bb = m >> 12;
  float4 acc = *(const float4*)(&bs[pq * 4]);
#pragma unroll
  for (int dy = -1; dy <= 1; ++dy) {
    const int hh = h + dy;
    if (hh < 0 || hh > 63) continue;
#pragma unroll
    for (int dx = -1; dx <= 1; ++dx) {
      const int ww = w + dx;
      if (ww < 0 || ww > 63) continue;
      const int idx = (dy + 1) * 3 + (dx + 1);
      const float4 v =
          *(const float4*)(y + (size_t)((bb << 12) + (hh << 6) + ww) * 256 + pq * 4);
      const float4 wv = *(const float4*)(&wt[idx][pq * 4]);
      acc.x += v.x * wv.x;
      acc.y += v.y * wv.y;
      acc.z += v.z * wv.z;
      acc.w += v.w * wv.w;
    }
  }
  *(float4*)(xm + (size_t)m * 256 + pq * 4) = acc;
}

// ---------------------------------------------------------------------------
// K3: xl = relu(xm @ lower_w^T + lb).
// ---------------------------------------------------------------------------
__global__ __launch_bounds__(256) void k_lower(const float* __restrict__ xm,
                                               const float* __restrict__ lw,
                                               const float* __restrict__ lb,
                                               float* __restrict__ xl) {
  __shared__ float As[64][68];
  __shared__ float Bs[64][68];
  const int t = threadIdx.x;
  const int m0 = blockIdx.x * 64, n0 = blockIdx.y * 64;
  const int rl = t >> 2, kq = t & 3;
  const int tn = t & 15, tm = t >> 4;
  float acc[4][4] = {};
  for (int kk = 0; kk < 256; kk += 64) {
    __syncthreads();
#pragma unroll
    for (int j = 0; j < 4; ++j) {
      const int f = kq + j * 4;
      const float4 a = *(const float4*)(xm + (size_t)(m0 + rl) * 256 + kk + f * 4);
      As[f * 4 + 0][rl] = a.x;
      As[f * 4 + 1][rl] = a.y;
      As[f * 4 + 2][rl] = a.z;
      As[f * 4 + 3][rl] = a.w;
      const float4 bq = *(const float4*)(lw + (size_t)(n0 + rl) * 256 + kk + f * 4);
      Bs[f * 4 + 0][rl] = bq.x;
      Bs[f * 4 + 1][rl] = bq.y;
      Bs[f * 4 + 2][rl] = bq.z;
      Bs[f * 4 + 3][rl] = bq.w;
    }
    __syncthreads();
#pragma unroll 8
    for (int k = 0; k < 64; ++k) {
      const float4 a = *(const float4*)(&As[k][tm * 4]);
      const float4 bb = *(const float4*)(&Bs[k][tn * 4]);
      const float av[4] = {a.x, a.y, a.z, a.w};
      const float bv[4] = {bb.x, bb.y, bb.z, bb.w};
#pragma unroll
      for (int i = 0; i < 4; ++i)
#pragma unroll
        for (int j = 0; j < 4; ++j) acc[i][j] += av[i] * bv[j];
    }
  }
  const float4 bias4 = *(const float4*)(lb + n0 + tn * 4);
  const float bias[4] = {bias4.x, bias4.y, bias4.z, bias4.w};
#pragma unroll
  for (int i = 0; i < 4; ++i) {
    float4 v;
    v.x = fmaxf(acc[i][0] + bias[0], 0.f);
    v.y = fmaxf(acc[i][1] + bias[1], 0.f);
    v.z = fmaxf(acc[i][2] + bias[2], 0.f);
    v.w = fmaxf(acc[i][3] + bias[3], 0.f);
    *(float4*)(xl + (size_t)(m0 + tm * 4 + i) * 256 + n0 + tn * 4) = v;
  }
}

// ---------------------------------------------------------------------------
// K4: per-pixel EM (d=1 collapsed). One wave per pixel; lane owns 4 n-rows.
// c[4][16] + b[16] + red[32] held fully in VGPRs: __launch_bounds__(256,2)
// caps at 256 VGPR (no spill; ~140 live). b-update uses recursive-halving
// reduce-scatter (32 shuffles/step vs 192 for all-reduce), leaving lane l
// with the total of reduction value (l&31); num/den pair via shfl_xor(16),
// then 16 constant-lane broadcasts rescale b[].
// ---------------------------------------------------------------------------
__global__ __launch_bounds__(256, 2) void k_em(const float* xl,
                                               const float* __restrict__ binit,
                                               const float* __restrict__ xmp,
                                               float* feat) {
  const int lane = threadIdx.x & 63;
  const int m = blockIdx.x * 4 + (threadIdx.x >> 6);
  const float4 s4 = *(const float4*)(xl + (size_t)m * 256 + lane * 4);
  const float s[4] = {s4.x, s4.y, s4.z, s4.w};
  float b[16];
#pragma unroll
  for (int r = 0; r < 16; ++r) {
    const float v = binit[m * 16 + r];
    b[r] = v / fmaxf(fabsf(v), 1e-12f);
  }
  // initial coef: softmax_r(s_n * b_r)
  float c[4][16];
#pragma unroll
  for (int i = 0; i < 4; ++i) {
    float mx = s[i] * b[0];
#pragma unroll
    for (int r = 1; r < 16; ++r) mx = fmaxf(mx, s[i] * b[r]);
    float sum = 0.f;
#pragma unroll
    for (int r = 0; r < 16; ++r) {
      const float e = __expf(s[i] * b[r] - mx);
      c[i][r] = e;
      sum += e;
    }
    const float inv = __fdividef(1.f, sum);
#pragma unroll
    for (int r = 0; r < 16; ++r) c[i][r] *= inv;
  }

  for (int step = 0; step < 6; ++step) {
    float red[32];
#pragma unroll
    for (int r = 0; r < 32; ++r) red[r] = 0.f;
    // coef update + partial accumulation
#pragma unroll
    for (int i = 0; i < 4; ++i) {
      float tt = 0.f;
#pragma unroll
      for (int r = 0; r < 16; ++r) tt += c[i][r] * b[r];
      float tp = 0.f;
#pragma unroll
      for (int r = 0; r < 16; ++r) {
        const float cn =
            c[i][r] * (s[i] * b[r]) * __frcp_rn(tt * b[r] + EPS);
        c[i][r] = cn;
        tp += cn * b[r];
        red[r] += s[i] * cn;
      }
#pragma unroll
      for (int r = 0; r < 16; ++r) red[16 + r] += tp * c[i][r];
    }
    // recursive-halving reduce-scatter: lane l ends with total of value l&31
    int cnt = 32;
#pragma unroll
    for (int k = 4; k >= 0; --k) {
      const int d = 1 << k;
      const bool up = (lane >> k) & 1;
      const int half = cnt >> 1;
#pragma unroll
      for (int j = 0; j < half; ++j) {
        const float lo = red[j], hi = red[j + half];
        const float send = up ? lo : hi;
        const float recv = __shfl_xor(send, d, 64);
        red[j] = (up ? hi : lo) + recv;
      }
      cnt = half;
    }
    float S = red[0] + __shfl_xor(red[0], 32, 64);
    // pair num (lanes l&16==0) with den (lanes l&16==1)
    const float dpart = __shfl_xor(S, 16, 64);
    const float q = S * __frcp_rn(dpart + EPS);
#pragma unroll
    for (int r = 0; r < 16; ++r) b[r] *= __shfl(q, r, 64);
  }

  // final coef refresh + xr + feat = relu(xm + xr)
  const float4 xm4 = *(const float4*)(xmp + (size_t)m * 256 + lane * 4);
  const float xmv[4] = {xm4.x, xm4.y, xm4.z, xm4.w};
  float o4[4];
#pragma unroll
  for (int i = 0; i < 4; ++i) {
    float tt = 0.f;
#pragma unroll
    for (int r = 0; r < 16; ++r) tt += c[i][r] * b[r];
    float xr = 0.f;
#pragma unroll
    for (int r = 0; r < 16; ++r) {
      const float cn =
          c[i][r] * (s[i] * b[r]) * __frcp_rn(tt * b[r] + EPS);
      xr += b[r] * cn;
    }
    o4[i] = fmaxf(xmv[i] + xr, 0.f);
  }
  const float4 outv = {o4[0], o4[1], o4[2], o4[3]};
  *(float4*)(feat + (size_t)m * 256 + lane * 4) = outv;
}

// ---------------------------------------------------------------------------
// K5: pooling phase 1
// ---------------------------------------------------------------------------
__global__ __launch_bounds__(256) void k_pool1(const float* __restrict__ feat,
                                               float* __restrict__ psum,
                                               float* __restrict__ pmax) {
  const int t = threadIdx.x;
  const int b = blockIdx.x >> 6;
  const int ch = blockIdx.x & 63;
  const float* fp = feat + (size_t)(b * 4096 + ch * 64) * 256 + t;
  float sum = 0.f, mx = -1e30f;
#pragma unroll 8
  for (int r = 0; r < 64; ++r) {
    const float v = fp[(size_t)r * 256];
    sum += v;
    mx = fmaxf(mx, v);
  }
  psum[(size_t)blockIdx.x * 256 + t] = sum;
  pmax[(size_t)blockIdx.x * 256 + t] = mx;
}

// ---------------------------------------------------------------------------
// K6: finish pooling + channel-attention MLP + sigmoid
// ---------------------------------------------------------------------------
__global__ __launch_bounds__(256) void k_att(const float* __restrict__ psum,
                                             const float* __restrict__ pmax,
                                             const float* __restrict__ ca1,
                                             const float* __restrict__ ca2,
                                             float* __restrict__ attv,
                                             float* __restrict__ out_att) {
  __shared__ float sA[256], sM[256], sH[64];
  const int t = threadIdx.x;
  const int b = blockIdx.x;
  float sum = 0.f, mx = -1e30f;
#pragma unroll 8
  for (int ch = 0; ch < 64; ++ch) {
    sum += psum[(size_t)(b * 64 + ch) * 256 + t];
    mx = fmaxf(mx, pmax[(size_t)(b * 64 + ch) * 256 + t]);
  }
  sA[t] = sum * (1.0f / 4096.0f);
  sM[t] = mx;
  __syncthreads();
  if (t < 64) {
    float ha = 0.f, hm = 0.f;
#pragma unroll 8
    for (int p = 0; p < 256; ++p) {
      const float w = ca1[t * 256 + p];
      ha += sA[p] * w;
      hm += sM[p] * w;
    }
    sH[t] = fmaxf(ha, 0.f) + fmaxf(hm, 0.f);
  }
  __syncthreads();
  float logit = 0.f;
#pragma unroll 8
  for (int a = 0; a < 64; ++a) logit += sH[a] * ca2[t * 64 + a];
  const float av = 1.0f / (1.0f + expf(-logit));
  attv[b * 256 + t] = av;
  out_att[b * 256 + t] = av;
}

// ---------------------------------------------------------------------------
// K7: out[b,o,hw] = sum_p feat[m,p]*att[b,p]*fc_w[o,p] + fc_b[o]
// ---------------------------------------------------------------------------
__global__ __launch_bounds__(256) void k_fc(const float* __restrict__ feat,
                                            const float* __restrict__ attv,
                                            const float* __restrict__ fw,
                                            const float* __restrict__ fb,
                                            float* __restrict__ out) {
  __shared__ float As[64][68];
  __shared__ float Bs[64][68];
  const int t = threadIdx.x;
  const int m0 = blockIdx.x * 64, o0 = blockIdx.y * 64;
  const int b = m0 >> 12, hw0 = m0 & 4095;
  const int rl = t >> 2, kq = t & 3;
  const int tm = t & 15, tn = t >> 4;
  float acc[4][4] = {};
  for (int kk = 0; kk < 256; kk += 64) {
    __syncthreads();
#pragma unroll
    for (int j = 0; j < 4; ++j) {
      const int f = kq + j * 4;
      const float4 a = *(const float4*)(feat + (size_t)(m0 + rl) * 256 + kk + f * 4);
      const float4 av = *(const float4*)(attv + b * 256 + kk + f * 4);
      As[f * 4 + 0][rl] = a.x * av.x;
      As[f * 4 + 1][rl] = a.y * av.y;
      As[f * 4 + 2][rl] = a.z * av.z;
      As[f * 4 + 3][rl] = a.w * av.w;
      const float4 bq = *(const float4*)(fw + (size_t)(o0 + rl) * 256 + kk + f * 4);
      Bs[f * 4 + 0][rl] = bq.x;
      Bs[f * 4 + 1][rl] = bq.y;
      Bs[f * 4 + 2][rl] = bq.z;
      Bs[f * 4 + 3][rl] = bq.w;
    }
    __syncthreads();
#pragma unroll 8
    for (int k = 0; k < 64; ++k) {
      const float4 a = *(const float4*)(&As[k][tm * 4]);
      const float4 bb = *(const float4*)(&Bs[k][tn * 4]);
      const float av[4] = {a.x, a.y, a.z, a.w};
      const float bv[4] = {bb.x, bb.y, bb.z, bb.w};
#pragma unroll
      for (int i = 0; i < 4; ++i)
#pragma unroll
        for (int j = 0; j < 4; ++j) acc[i][j] += av[i] * bv[j];
    }
  }
#pragma unroll
  for (int j = 0; j < 4; ++j) {
    const int o = o0 + tn * 4 + j;
    const float bias = fb[o];
    const float4 v = {acc[0][j] + bias, acc[1][j] + bias, acc[2][j] + bias,
                      acc[3][j] + bias};
    *(float4*)(out + (size_t)b * 524288 + (size_t)o * 4096 + hw0 + tm * 4) = v;
  }
}

extern "C" void kernel_launch(void* const* d_in, const int* in_sizes, int n_in,
                              void* d_out, int out_size, void* d_ws, size_t ws_size,
                              hipStream_t stream) {
  const float* x = (const float*)d_in[0];
  const float* w1 = (const float*)d_in[1];
  const float* w3 = (const float*)d_in[2];
  const float* b3 = (const float*)d_in[3];
  const float* lw = (const float*)d_in[4];
  const float* lb = (const float*)d_in[5];
  const float* ca1 = (const float*)d_in[6];
  const float* ca2 = (const float*)d_in[7];
  const float* fw = (const float*)d_in[8];
  const float* fb = (const float*)d_in[9];
  const float* binit = (const float*)d_in[10];

  float* ws = (float*)d_ws;
  float* bufA = ws;            // y -> xl -> feat   (M*256)
  float* bufB = ws + 4194304;  // xm                (M*256)
  float* psum = ws + 8388608;  // 4*64*256
  float* pmax = psum + 65536;
  float* attv = pmax + 65536;  // 1024
  float* out = (float*)d_out;
  float* out_att = out + 2097152;

  const dim3 blk(256);
  k_conv1x1<<<dim3(256, 4), blk, 0, stream>>>(x, w1, bufA);
  k_dwconv<<<dim3(4096), blk, 0, stream>>>(bufA, w3, b3, bufB);
  k_lower<<<dim3(256, 4), blk, 0, stream>>>(bufB, lw, lb, bufA);
  k_em<<<dim3(4096), blk, 0, stream>>>(bufA, binit, bufB, bufA);
  k_pool1<<<dim3(256), blk, 0, stream>>>(bufA, psum, pmax);
  k_att<<<dim3(4), blk, 0, stream>>>(psum, pmax, ca1, ca2, attv, out_att);
  k_fc<<<dim3(256, 2), blk, 0, stream>>>(bufA, attv, fw, fb, out);
}